// Round 1
// baseline (192.376 us; speedup 1.0000x reference)
//
#include <hip/hip_runtime.h>

typedef unsigned short u16;
typedef unsigned int u32;
typedef __attribute__((ext_vector_type(8))) __bf16 bf16x8;
typedef __attribute__((ext_vector_type(4))) float f32x4;
typedef __attribute__((ext_vector_type(4))) u32 u32x4;

__device__ __forceinline__ u16 f2bf(float f) {
  u32 u = __builtin_bit_cast(u32, f);
  u = (u + 0x7fffu + ((u >> 16) & 1u)) >> 16;
  return (u16)u;
}
__device__ __forceinline__ float bf2f(u16 h) {
  return __builtin_bit_cast(float, (u32)h << 16);
}

// ---------------- fp32 -> bf16 convert (x) ----------------
__global__ __launch_bounds__(256) void conv_x_k(const float* __restrict__ x, u16* __restrict__ xb, int n) {
  int i = (blockIdx.x * 256 + threadIdx.x) * 8;
  if (i >= n) return;
  u16 tmp[8];
  #pragma unroll
  for (int j = 0; j < 8; ++j) tmp[j] = f2bf(x[i + j]);
  *(u32x4*)(&xb[i]) = *(u32x4*)tmp;
}

// ---------------- weight transpose + bf16 convert: wt[n][k] = bf16(w[k][n]) ----------------
__global__ __launch_bounds__(256) void conv_wt_k(const float* w0, const float* w1, const float* w2, const float* w3,
                                                 u16* o0, u16* o1, u16* o2, u16* o3) {
  const float* w = blockIdx.z == 0 ? w0 : blockIdx.z == 1 ? w1 : blockIdx.z == 2 ? w2 : w3;
  u16* o = blockIdx.z == 0 ? o0 : blockIdx.z == 1 ? o1 : blockIdx.z == 2 ? o2 : o3;
  __shared__ float tile[32][33];
  int tx = threadIdx.x & 31, ty = threadIdx.x >> 5;
  int n0 = blockIdx.x * 32, k0 = blockIdx.y * 32;
  #pragma unroll
  for (int j = 0; j < 4; ++j) tile[ty + j*8][tx] = w[(size_t)(k0 + ty + j*8) * 1024 + n0 + tx];
  __syncthreads();
  #pragma unroll
  for (int j = 0; j < 4; ++j) o[(size_t)(n0 + ty + j*8) * 1024 + k0 + tx] = f2bf(tile[tx][ty + j*8]);
}

// ---------------- cos/sin table: trig[(l*32+j)*2 + {0,1}] ----------------
__global__ __launch_bounds__(256) void trig_k(float* __restrict__ trig) {
  int idx = blockIdx.x * 256 + threadIdx.x;  // l*32 + j over 2048*32
  int l = idx >> 5, j = idx & 31;
  float invf = powf(10000.0f, -(float)j * (1.0f / 32.0f));
  float ang = (float)l * invf;
  trig[idx * 2 + 0] = cosf(ang);
  trig[idx * 2 + 1] = sinf(ang);
}

// ---------------- GEMM: C[M][N] = A[M][K] @ Bt[N][K]^T  (bf16 in, fp32 acc) ----------------
// 128x128 tile, BK=32, 4 waves, each wave 64x64 = 4x4 frags of 16x16x32 MFMA.
template<bool OUT_BF16>
__global__ __launch_bounds__(256) void gemm_bt(const u16* __restrict__ A,
    const u16* __restrict__ B0, const u16* __restrict__ B1, const u16* __restrict__ B2,
    void* C0, void* C1, void* C2, int M, int N, int K)
{
  const u16* B = blockIdx.z == 0 ? B0 : blockIdx.z == 1 ? B1 : B2;
  void* Cv = blockIdx.z == 0 ? C0 : blockIdx.z == 1 ? C1 : C2;
  __shared__ __align__(16) u16 As[128][40];   // +8 pad: frag reads 2-way max
  __shared__ __align__(16) u16 Bs[128][40];
  const int t = threadIdx.x;
  const int lane = t & 63, w = t >> 6;
  const int la = lane & 15, lb = lane >> 4;
  const int wr = (w >> 1) * 64, wc = (w & 1) * 64;
  const int brow = blockIdx.y * 128, bcol = blockIdx.x * 128;
  f32x4 acc[4][4];
  #pragma unroll
  for (int m = 0; m < 4; ++m)
    #pragma unroll
    for (int n = 0; n < 4; ++n) acc[m][n] = (f32x4){0.f, 0.f, 0.f, 0.f};
  const int ra = t >> 2, ca = (t & 3) * 8;   // staging: 64 rows per issue, 4x8 cols
  for (int k0 = 0; k0 < K; k0 += 32) {
    #pragma unroll
    for (int i = 0; i < 2; ++i) {
      int r = i * 64 + ra;
      *(u32x4*)(&As[r][ca]) = *(const u32x4*)(&A[(size_t)(brow + r) * K + k0 + ca]);
      *(u32x4*)(&Bs[r][ca]) = *(const u32x4*)(&B[(size_t)(bcol + r) * K + k0 + ca]);
    }
    __syncthreads();
    bf16x8 af[4], bff[4];
    #pragma unroll
    for (int m = 0; m < 4; ++m) af[m] = __builtin_bit_cast(bf16x8, *(const u32x4*)(&As[wr + m*16 + la][lb*8]));
    #pragma unroll
    for (int n = 0; n < 4; ++n) bff[n] = __builtin_bit_cast(bf16x8, *(const u32x4*)(&Bs[wc + n*16 + la][lb*8]));
    #pragma unroll
    for (int m = 0; m < 4; ++m)
      #pragma unroll
      for (int n = 0; n < 4; ++n)
        acc[m][n] = __builtin_amdgcn_mfma_f32_16x16x32_bf16(af[m], bff[n], acc[m][n], 0, 0, 0);
    __syncthreads();
  }
  // C/D layout: row = (lane>>4)*4 + j, col = lane&15  [m89]
  #pragma unroll
  for (int m = 0; m < 4; ++m) {
    int r = brow + wr + m * 16 + lb * 4;
    #pragma unroll
    for (int n = 0; n < 4; ++n) {
      int cc = bcol + wc + n * 16 + la;
      #pragma unroll
      for (int j = 0; j < 4; ++j) {
        if (OUT_BF16) ((u16*)Cv)[(size_t)(r + j) * N + cc] = f2bf(acc[m][n][j]);
        else          ((float*)Cv)[(size_t)(r + j) * N + cc] = acc[m][n][j];
      }
    }
  }
}

// ---------------- RoPE + ReLU in place on bf16 q,k ----------------
__global__ __launch_bounds__(256) void rope_relu_k(u16* __restrict__ Qb, u16* __restrict__ Kb,
                                                   const float* __restrict__ trig) {
  int p = blockIdx.x * 256 + threadIdx.x;  // pair index over 2 * 2048*512
  u16* buf = (p < (1 << 20)) ? Qb : Kb;
  int pp = p & ((1 << 20) - 1);            // l*512 + h*32 + j
  int l = pp >> 9, j = pp & 31;
  u32 v = *(u32*)(&buf[2 * pp]);
  float x1 = bf2f((u16)(v & 0xffff)), x2 = bf2f((u16)(v >> 16));
  float cs = trig[(l * 32 + j) * 2], sn = trig[(l * 32 + j) * 2 + 1];
  float y1 = fmaxf(x1 * cs - x2 * sn, 0.f);
  float y2 = fmaxf(x1 * sn + x2 * cs, 0.f);
  *(u32*)(&buf[2 * pp]) = (u32)f2bf(y1) | ((u32)f2bf(y2) << 16);
}

// ---------------- per-chunk KV sums: S[c][h][d][m] = sum_i K[i][d]*V[i][m]; ksum[c][h][d] ----------------
__global__ __launch_bounds__(256) void chunk_kv_k(const u16* __restrict__ Kb, const u16* __restrict__ Vb,
                                                  float* __restrict__ S, float* __restrict__ ksum) {
  int c = blockIdx.x, h = blockIdx.y;
  __shared__ __align__(16) float Ks[64][68];
  __shared__ __align__(16) float Vs[64][68];
  int t = threadIdx.x;
  #pragma unroll
  for (int i = 0; i < 2; ++i) {
    int r = i * 32 + (t >> 3), col = (t & 7) * 8;
    size_t g = (size_t)(c * 64 + r) * 1024 + h * 64 + col;
    u32x4 kk = *(const u32x4*)(&Kb[g]);
    u32x4 vv = *(const u32x4*)(&Vb[g]);
    const u16* kp_ = (const u16*)&kk;
    const u16* vp_ = (const u16*)&vv;
    #pragma unroll
    for (int j2 = 0; j2 < 8; ++j2) { Ks[r][col + j2] = bf2f(kp_[j2]); Vs[r][col + j2] = bf2f(vp_[j2]); }
  }
  __syncthreads();
  int d = t >> 2, mb = (t & 3) * 16;
  float acc[16];
  #pragma unroll
  for (int m = 0; m < 16; ++m) acc[m] = 0.f;
  float ksv = 0.f;
  for (int i = 0; i < 64; ++i) {
    float kd = Ks[i][d];
    ksv += kd;
    #pragma unroll
    for (int q4 = 0; q4 < 4; ++q4) {
      float4 v4 = *(const float4*)(&Vs[i][mb + q4 * 4]);
      acc[q4*4+0] += kd * v4.x; acc[q4*4+1] += kd * v4.y;
      acc[q4*4+2] += kd * v4.z; acc[q4*4+3] += kd * v4.w;
    }
  }
  size_t base = ((size_t)(c * 16 + h) * 64 + d) * 64 + mb;
  #pragma unroll
  for (int m = 0; m < 16; ++m) S[base + m] = acc[m];
  if ((t & 3) == 0) ksum[(c * 16 + h) * 64 + d] = ksv;
}

// ---------------- exclusive chunk prefix: Pt[c][h][m][d] (bf16), kp[c][h][d] (f32) ----------------
__global__ __launch_bounds__(256) void prefix_k(const float* __restrict__ S, const float* __restrict__ ksum,
                                                u16* __restrict__ Pt, float* __restrict__ kp) {
  int h = blockIdx.x, t = threadIdx.x;
  for (int e = t; e < 4096; e += 256) {   // e = m*64 + d (Pt-flat, coalesced writes)
    int d = e & 63, m = e >> 6;
    float run = 0.f;
    for (int c = 0; c < 32; ++c) {
      size_t cb = (size_t)(c * 16 + h) << 12;
      Pt[cb + e] = f2bf(run);
      run += S[cb + d * 64 + m];
    }
  }
  if (t < 64) {
    float run = 0.f;
    for (int c = 0; c < 32; ++c) {
      kp[(c * 16 + h) * 64 + t] = run;
      run += ksum[(c * 16 + h) * 64 + t];
    }
  }
}

// ---------------- per-chunk output: num = tril(QK^T)@V + Q@P ; den = rowsum + Q.kp ----------------
__global__ __launch_bounds__(256) void chunk_out_k(const u16* __restrict__ Qb, const u16* __restrict__ Kb,
    const u16* __restrict__ Vb, const u16* __restrict__ Pt, const float* __restrict__ kp,
    u16* __restrict__ attnb)
{
  int c = blockIdx.x, h = blockIdx.y;
  __shared__ __align__(16) u16 Qs[64][72];
  __shared__ __align__(16) u16 Ks2[64][72];
  __shared__ __align__(16) u16 Vt[64][72];   // Vt[m][i] = V[i][m]
  __shared__ __align__(16) u16 Pts[64][72];  // Pts[m][d]
  __shared__ __align__(16) u16 Am[64][72];   // masked QK^T, bf16
  __shared__ float den_s[64];
  __shared__ float kps[64];
  const int t = threadIdx.x;
  const int lane = t & 63, w = t >> 6;
  const int la = lane & 15, lb = lane >> 4;
  #pragma unroll
  for (int i = 0; i < 2; ++i) {
    int r = i * 32 + (t >> 3), col = (t & 7) * 8;
    size_t g = (size_t)(c * 64 + r) * 1024 + h * 64 + col;
    *(u32x4*)(&Qs[r][col]) = *(const u32x4*)(&Qb[g]);
    *(u32x4*)(&Ks2[r][col]) = *(const u32x4*)(&Kb[g]);
    u32x4 vv = *(const u32x4*)(&Vb[g]);
    const u16* vp_ = (const u16*)&vv;
    #pragma unroll
    for (int j2 = 0; j2 < 8; ++j2) {        // lane-rotated j to spread banks
      int jj = (j2 + t) & 7;
      Vt[col + jj][r] = vp_[jj];
    }
    *(u32x4*)(&Pts[r][col]) = *(const u32x4*)(&Pt[(((size_t)(c * 16 + h)) << 12) + (size_t)r * 64 + col]);
  }
  if (t < 64) kps[t] = kp[(c * 16 + h) * 64 + t];
  __syncthreads();
  // phase A: Am = tril(Q @ K^T)
  {
    const int wr = (w >> 1) * 32, wc = (w & 1) * 32;
    f32x4 acc[2][2];
    #pragma unroll
    for (int m = 0; m < 2; ++m)
      #pragma unroll
      for (int n = 0; n < 2; ++n) acc[m][n] = (f32x4){0.f, 0.f, 0.f, 0.f};
    #pragma unroll
    for (int ks = 0; ks < 2; ++ks) {
      bf16x8 af[2], bff[2];
      #pragma unroll
      for (int m = 0; m < 2; ++m) af[m] = __builtin_bit_cast(bf16x8, *(const u32x4*)(&Qs[wr + m*16 + la][ks*32 + lb*8]));
      #pragma unroll
      for (int n = 0; n < 2; ++n) bff[n] = __builtin_bit_cast(bf16x8, *(const u32x4*)(&Ks2[wc + n*16 + la][ks*32 + lb*8]));
      #pragma unroll
      for (int m = 0; m < 2; ++m)
        #pragma unroll
        for (int n = 0; n < 2; ++n)
          acc[m][n] = __builtin_amdgcn_mfma_f32_16x16x32_bf16(af[m], bff[n], acc[m][n], 0, 0, 0);
    }
    #pragma unroll
    for (int m = 0; m < 2; ++m)
      #pragma unroll
      for (int n = 0; n < 2; ++n) {
        int col = wc + n * 16 + la;
        #pragma unroll
        for (int j = 0; j < 4; ++j) {
          int r = wr + m * 16 + lb * 4 + j;
          Am[r][col] = f2bf(col <= r ? acc[m][n][j] : 0.f);
        }
      }
  }
  __syncthreads();
  // denominator: den[l] = sum_i Am[l][i] + Q[l].kp
  {
    int l = t >> 2, q = t & 3;
    float s = 0.f;
    #pragma unroll
    for (int i = 0; i < 16; ++i) s += bf2f(Am[l][q * 16 + i]);
    s += __shfl_xor(s, 1);
    s += __shfl_xor(s, 2);
    if (q == 0) {
      float qk = 0.f;
      for (int d = 0; d < 64; ++d) qk += bf2f(Qs[l][d]) * kps[d];
      den_s[l] = s + qk;
    }
  }
  __syncthreads();
  // phase B: num = Am @ V + Q @ P ; write attn = num/(den+eps)
  {
    const int row0 = w * 16;
    f32x4 acc[4];
    #pragma unroll
    for (int n = 0; n < 4; ++n) acc[n] = (f32x4){0.f, 0.f, 0.f, 0.f};
    #pragma unroll
    for (int ks = 0; ks < 2; ++ks) {
      bf16x8 a1 = __builtin_bit_cast(bf16x8, *(const u32x4*)(&Am[row0 + la][ks*32 + lb*8]));
      bf16x8 a2 = __builtin_bit_cast(bf16x8, *(const u32x4*)(&Qs[row0 + la][ks*32 + lb*8]));
      #pragma unroll
      for (int n = 0; n < 4; ++n) {
        bf16x8 b1 = __builtin_bit_cast(bf16x8, *(const u32x4*)(&Vt[n*16 + la][ks*32 + lb*8]));
        acc[n] = __builtin_amdgcn_mfma_f32_16x16x32_bf16(a1, b1, acc[n], 0, 0, 0);
        bf16x8 b2 = __builtin_bit_cast(bf16x8, *(const u32x4*)(&Pts[n*16 + la][ks*32 + lb*8]));
        acc[n] = __builtin_amdgcn_mfma_f32_16x16x32_bf16(a2, b2, acc[n], 0, 0, 0);
      }
    }
    #pragma unroll
    for (int n = 0; n < 4; ++n) {
      int col = n * 16 + la;
      #pragma unroll
      for (int j = 0; j < 4; ++j) {
        int r = row0 + lb * 4 + j;
        float v = acc[n][j] / (den_s[r] + 1e-6f);
        attnb[(size_t)(c * 64 + r) * 1024 + h * 64 + col] = f2bf(v);
      }
    }
  }
}

extern "C" void kernel_launch(void* const* d_in, const int* in_sizes, int n_in,
                              void* d_out, int out_size, void* d_ws, size_t ws_size,
                              hipStream_t stream) {
  const float* x  = (const float*)d_in[0];
  const float* wq = (const float*)d_in[1];
  const float* wk = (const float*)d_in[2];
  const float* wv = (const float*)d_in[3];
  const float* wo = (const float*)d_in[4];
  float* out = (float*)d_out;
  char* ws = (char*)d_ws;
  const size_t MB = 1024 * 1024;
  u16*   xb    = (u16*)(ws + 0 * MB);         // 4 MB
  u16*   wqt   = (u16*)(ws + 4 * MB);         // 2 MB
  u16*   wkt   = (u16*)(ws + 6 * MB);         // 2 MB
  u16*   wvt   = (u16*)(ws + 8 * MB);         // 2 MB
  u16*   wot   = (u16*)(ws + 10 * MB);        // 2 MB
  u16*   Qb    = (u16*)(ws + 12 * MB);        // 4 MB
  u16*   Kb    = (u16*)(ws + 16 * MB);        // 4 MB
  u16*   Vb    = (u16*)(ws + 20 * MB);        // 4 MB
  float* S     = (float*)(ws + 24 * MB);      // 8 MB  (32 chunks x 16 h x 64 x 64)
  u16*   Pt    = (u16*)(ws + 32 * MB);        // 4 MB
  float* ksum  = (float*)(ws + 36 * MB);      // 128 KB
  float* kp    = (float*)(ws + 36 * MB + 128 * 1024); // 128 KB
  u16*   attnb = (u16*)(ws + 37 * MB);        // 4 MB
  float* trig  = (float*)(ws + 41 * MB);      // 512 KB

  conv_x_k<<<1024, 256, 0, stream>>>(x, xb, 2048 * 1024);
  conv_wt_k<<<dim3(32, 32, 4), 256, 0, stream>>>(wq, wk, wv, wo, wqt, wkt, wvt, wot);
  trig_k<<<256, 256, 0, stream>>>(trig);
  gemm_bt<true><<<dim3(8, 16, 3), 256, 0, stream>>>(xb, wqt, wkt, wvt, (void*)Qb, (void*)Kb, (void*)Vb,
                                                    2048, 1024, 1024);
  rope_relu_k<<<8192, 256, 0, stream>>>(Qb, Kb, trig);
  chunk_kv_k<<<dim3(32, 16), 256, 0, stream>>>(Kb, Vb, S, ksum);
  prefix_k<<<16, 256, 0, stream>>>(S, ksum, Pt, kp);
  chunk_out_k<<<dim3(32, 16), 256, 0, stream>>>(Qb, Kb, Vb, Pt, kp, attnb);
  gemm_bt<false><<<dim3(8, 16, 1), 256, 0, stream>>>(attnb, wot, wot, wot, (void*)out, (void*)out, (void*)out,
                                                     2048, 1024, 1024);
}

// Round 2
// 122.855 us; speedup vs baseline: 1.5659x; 1.5659x over previous
//
#include <hip/hip_runtime.h>

typedef unsigned short u16;
typedef unsigned int u32;
typedef __attribute__((ext_vector_type(8))) __bf16 bf16x8;
typedef __attribute__((ext_vector_type(4))) float f32x4;
typedef __attribute__((ext_vector_type(4))) u32 u32x4;

__device__ __forceinline__ u16 f2bf(float f) {
  u32 u = __builtin_bit_cast(u32, f);
  u = (u + 0x7fffu + ((u >> 16) & 1u)) >> 16;
  return (u16)u;
}
__device__ __forceinline__ float bf2f(u16 h) {
  return __builtin_bit_cast(float, (u32)h << 16);
}

// ---------------- fp32 -> bf16 convert (x) ----------------
__global__ __launch_bounds__(256) void conv_x_k(const float* __restrict__ x, u16* __restrict__ xb, int n) {
  int i = (blockIdx.x * 256 + threadIdx.x) * 8;
  if (i >= n) return;
  u16 tmp[8];
  #pragma unroll
  for (int j = 0; j < 8; ++j) tmp[j] = f2bf(x[i + j]);
  *(u32x4*)(&xb[i]) = *(u32x4*)tmp;
}

// ---------------- weight transpose + bf16 convert: wt[n][k] = bf16(w[k][n]) ----------------
__global__ __launch_bounds__(256) void conv_wt_k(const float* w0, const float* w1, const float* w2, const float* w3,
                                                 u16* o0, u16* o1, u16* o2, u16* o3) {
  const float* w = blockIdx.z == 0 ? w0 : blockIdx.z == 1 ? w1 : blockIdx.z == 2 ? w2 : w3;
  u16* o = blockIdx.z == 0 ? o0 : blockIdx.z == 1 ? o1 : blockIdx.z == 2 ? o2 : o3;
  __shared__ float tile[32][33];
  int tx = threadIdx.x & 31, ty = threadIdx.x >> 5;
  int n0 = blockIdx.x * 32, k0 = blockIdx.y * 32;
  #pragma unroll
  for (int j = 0; j < 4; ++j) tile[ty + j*8][tx] = w[(size_t)(k0 + ty + j*8) * 1024 + n0 + tx];
  __syncthreads();
  #pragma unroll
  for (int j = 0; j < 4; ++j) o[(size_t)(n0 + ty + j*8) * 1024 + k0 + tx] = f2bf(tile[tx][ty + j*8]);
}

// ---------------- cos/sin table: trig[(l*32+j)*2 + {0,1}] ----------------
__global__ __launch_bounds__(256) void trig_k(float* __restrict__ trig) {
  int idx = blockIdx.x * 256 + threadIdx.x;  // l*32 + j over 2048*32
  int l = idx >> 5, j = idx & 31;
  float invf = powf(10000.0f, -(float)j * (1.0f / 32.0f));
  float ang = (float)l * invf;
  trig[idx * 2 + 0] = cosf(ang);
  trig[idx * 2 + 1] = sinf(ang);
}

// ---------------- GEMM: C[M][N] = A[M][K] @ Bt[N][K]^T  (bf16 in, fp32 acc) ----------------
// 128x128 tile, BK=32, 4 waves, each wave 64x64 = 4x4 frags of 16x16x32 MFMA.
template<bool OUT_BF16>
__global__ __launch_bounds__(256) void gemm_bt(const u16* __restrict__ A,
    const u16* __restrict__ B0, const u16* __restrict__ B1, const u16* __restrict__ B2,
    void* C0, void* C1, void* C2, int M, int N, int K)
{
  const u16* B = blockIdx.z == 0 ? B0 : blockIdx.z == 1 ? B1 : B2;
  void* Cv = blockIdx.z == 0 ? C0 : blockIdx.z == 1 ? C1 : C2;
  __shared__ __align__(16) u16 As[128][40];   // +8 pad: frag reads 2-way max
  __shared__ __align__(16) u16 Bs[128][40];
  const int t = threadIdx.x;
  const int lane = t & 63, w = t >> 6;
  const int la = lane & 15, lb = lane >> 4;
  const int wr = (w >> 1) * 64, wc = (w & 1) * 64;
  const int brow = blockIdx.y * 128, bcol = blockIdx.x * 128;
  f32x4 acc[4][4];
  #pragma unroll
  for (int m = 0; m < 4; ++m)
    #pragma unroll
    for (int n = 0; n < 4; ++n) acc[m][n] = (f32x4){0.f, 0.f, 0.f, 0.f};
  const int ra = t >> 2, ca = (t & 3) * 8;   // staging: 64 rows per issue, 4x8 cols
  for (int k0 = 0; k0 < K; k0 += 32) {
    #pragma unroll
    for (int i = 0; i < 2; ++i) {
      int r = i * 64 + ra;
      *(u32x4*)(&As[r][ca]) = *(const u32x4*)(&A[(size_t)(brow + r) * K + k0 + ca]);
      *(u32x4*)(&Bs[r][ca]) = *(const u32x4*)(&B[(size_t)(bcol + r) * K + k0 + ca]);
    }
    __syncthreads();
    bf16x8 af[4], bff[4];
    #pragma unroll
    for (int m = 0; m < 4; ++m) af[m] = __builtin_bit_cast(bf16x8, *(const u32x4*)(&As[wr + m*16 + la][lb*8]));
    #pragma unroll
    for (int n = 0; n < 4; ++n) bff[n] = __builtin_bit_cast(bf16x8, *(const u32x4*)(&Bs[wc + n*16 + la][lb*8]));
    #pragma unroll
    for (int m = 0; m < 4; ++m)
      #pragma unroll
      for (int n = 0; n < 4; ++n)
        acc[m][n] = __builtin_amdgcn_mfma_f32_16x16x32_bf16(af[m], bff[n], acc[m][n], 0, 0, 0);
    __syncthreads();
  }
  // C/D layout: row = (lane>>4)*4 + j, col = lane&15  [m89]
  #pragma unroll
  for (int m = 0; m < 4; ++m) {
    int r = brow + wr + m * 16 + lb * 4;
    #pragma unroll
    for (int n = 0; n < 4; ++n) {
      int cc = bcol + wc + n * 16 + la;
      #pragma unroll
      for (int j = 0; j < 4; ++j) {
        if (OUT_BF16) ((u16*)Cv)[(size_t)(r + j) * N + cc] = f2bf(acc[m][n][j]);
        else          ((float*)Cv)[(size_t)(r + j) * N + cc] = acc[m][n][j];
      }
    }
  }
}

// ---------------- RoPE + ReLU in place on bf16 q,k ----------------
__global__ __launch_bounds__(256) void rope_relu_k(u16* __restrict__ Qb, u16* __restrict__ Kb,
                                                   const float* __restrict__ trig) {
  int p = blockIdx.x * 256 + threadIdx.x;  // pair index over 2 * 2048*512
  u16* buf = (p < (1 << 20)) ? Qb : Kb;
  int pp = p & ((1 << 20) - 1);            // l*512 + h*32 + j
  int l = pp >> 9, j = pp & 31;
  u32 v = *(u32*)(&buf[2 * pp]);
  float x1 = bf2f((u16)(v & 0xffff)), x2 = bf2f((u16)(v >> 16));
  float cs = trig[(l * 32 + j) * 2], sn = trig[(l * 32 + j) * 2 + 1];
  float y1 = fmaxf(x1 * cs - x2 * sn, 0.f);
  float y2 = fmaxf(x1 * sn + x2 * cs, 0.f);
  *(u32*)(&buf[2 * pp]) = (u32)f2bf(y1) | ((u32)f2bf(y2) << 16);
}

// ---------------- per-chunk KV sums: S[c][h][m][d] = sum_i K[i][d]*V[i][m]; ksum[c][h][d] ----------------
__global__ __launch_bounds__(256) void chunk_kv_k(const u16* __restrict__ Kb, const u16* __restrict__ Vb,
                                                  float* __restrict__ S, float* __restrict__ ksum) {
  int c = blockIdx.x, h = blockIdx.y;
  __shared__ __align__(16) float Ks[64][68];
  __shared__ __align__(16) float Vs[64][68];
  int t = threadIdx.x;
  #pragma unroll
  for (int i = 0; i < 2; ++i) {
    int r = i * 32 + (t >> 3), col = (t & 7) * 8;
    size_t g = (size_t)(c * 64 + r) * 1024 + h * 64 + col;
    u32x4 kk = *(const u32x4*)(&Kb[g]);
    u32x4 vv = *(const u32x4*)(&Vb[g]);
    const u16* kp_ = (const u16*)&kk;
    const u16* vp_ = (const u16*)&vv;
    #pragma unroll
    for (int j2 = 0; j2 < 8; ++j2) { Ks[r][col + j2] = bf2f(kp_[j2]); Vs[r][col + j2] = bf2f(vp_[j2]); }
  }
  __syncthreads();
  // thread owns one m (row of S[c][h][m][:]), 16 consecutive d
  int m = t >> 2, db = (t & 3) * 16;
  float acc[16];
  #pragma unroll
  for (int d = 0; d < 16; ++d) acc[d] = 0.f;
  for (int i = 0; i < 64; ++i) {
    float vm = Vs[i][m];
    #pragma unroll
    for (int q4 = 0; q4 < 4; ++q4) {
      float4 k4 = *(const float4*)(&Ks[i][db + q4 * 4]);
      acc[q4*4+0] += vm * k4.x; acc[q4*4+1] += vm * k4.y;
      acc[q4*4+2] += vm * k4.z; acc[q4*4+3] += vm * k4.w;
    }
  }
  size_t base = ((size_t)(c * 16 + h) * 64 + m) * 64 + db;
  #pragma unroll
  for (int q4 = 0; q4 < 4; ++q4) *(float4*)(&S[base + q4 * 4]) = *(float4*)(&acc[q4 * 4]);
  if (t < 64) {
    float s = 0.f;
    for (int i = 0; i < 64; ++i) s += Ks[i][t];
    ksum[(c * 16 + h) * 64 + t] = s;
  }
}

// ---------------- exclusive chunk prefix: Pt[c][h][m][d] (bf16), kp[c][h][d] (f32) ----------------
// one thread per (h, e=m*64+d); 65536 threads; fully unrolled 32-chunk scan, coalesced both sides
__global__ __launch_bounds__(256) void prefix_k(const float* __restrict__ S, const float* __restrict__ ksum,
                                                u16* __restrict__ Pt, float* __restrict__ kp) {
  int idx = blockIdx.x * 256 + threadIdx.x;   // over 16*4096
  int h = idx >> 12, e = idx & 4095;
  float run = 0.f;
  #pragma unroll
  for (int c = 0; c < 32; ++c) {
    size_t cb = (size_t)(c * 16 + h) << 12;
    Pt[cb + e] = f2bf(run);
    run += S[cb + e];
  }
  if (idx < 1024) {
    int hh = idx >> 6, dd = idx & 63;
    float r2 = 0.f;
    #pragma unroll
    for (int c = 0; c < 32; ++c) {
      kp[(c * 16 + hh) * 64 + dd] = r2;
      r2 += ksum[(c * 16 + hh) * 64 + dd];
    }
  }
}

// ---------------- per-chunk output: num = tril(QK^T)@V + Q@P ; den = rowsum + Q.kp ----------------
__global__ __launch_bounds__(256) void chunk_out_k(const u16* __restrict__ Qb, const u16* __restrict__ Kb,
    const u16* __restrict__ Vb, const u16* __restrict__ Pt, const float* __restrict__ kp,
    u16* __restrict__ attnb)
{
  int c = blockIdx.x, h = blockIdx.y;
  __shared__ __align__(16) u16 Qs[64][72];
  __shared__ __align__(16) u16 Ks2[64][72];
  __shared__ __align__(16) u16 Vt[64][72];   // Vt[m][i] = V[i][m]
  __shared__ __align__(16) u16 Pts[64][72];  // Pts[m][d]
  __shared__ __align__(16) u16 Am[64][72];   // masked QK^T, bf16
  __shared__ float den_s[64];
  __shared__ float kps[64];
  const int t = threadIdx.x;
  const int lane = t & 63, w = t >> 6;
  const int la = lane & 15, lb = lane >> 4;
  #pragma unroll
  for (int i = 0; i < 2; ++i) {
    int r = i * 32 + (t >> 3), col = (t & 7) * 8;
    size_t g = (size_t)(c * 64 + r) * 1024 + h * 64 + col;
    *(u32x4*)(&Qs[r][col]) = *(const u32x4*)(&Qb[g]);
    *(u32x4*)(&Ks2[r][col]) = *(const u32x4*)(&Kb[g]);
    u32x4 vv = *(const u32x4*)(&Vb[g]);
    const u16* vp_ = (const u16*)&vv;
    #pragma unroll
    for (int j2 = 0; j2 < 8; ++j2) {        // lane-rotated j to spread banks
      int jj = (j2 + t) & 7;
      Vt[col + jj][r] = vp_[jj];
    }
    *(u32x4*)(&Pts[r][col]) = *(const u32x4*)(&Pt[(((size_t)(c * 16 + h)) << 12) + (size_t)r * 64 + col]);
  }
  if (t < 64) kps[t] = kp[(c * 16 + h) * 64 + t];
  __syncthreads();
  // phase A: Am = tril(Q @ K^T)
  {
    const int wr = (w >> 1) * 32, wc = (w & 1) * 32;
    f32x4 acc[2][2];
    #pragma unroll
    for (int m = 0; m < 2; ++m)
      #pragma unroll
      for (int n = 0; n < 2; ++n) acc[m][n] = (f32x4){0.f, 0.f, 0.f, 0.f};
    #pragma unroll
    for (int ks = 0; ks < 2; ++ks) {
      bf16x8 af[2], bff[2];
      #pragma unroll
      for (int m = 0; m < 2; ++m) af[m] = __builtin_bit_cast(bf16x8, *(const u32x4*)(&Qs[wr + m*16 + la][ks*32 + lb*8]));
      #pragma unroll
      for (int n = 0; n < 2; ++n) bff[n] = __builtin_bit_cast(bf16x8, *(const u32x4*)(&Ks2[wc + n*16 + la][ks*32 + lb*8]));
      #pragma unroll
      for (int m = 0; m < 2; ++m)
        #pragma unroll
        for (int n = 0; n < 2; ++n)
          acc[m][n] = __builtin_amdgcn_mfma_f32_16x16x32_bf16(af[m], bff[n], acc[m][n], 0, 0, 0);
    }
    #pragma unroll
    for (int m = 0; m < 2; ++m)
      #pragma unroll
      for (int n = 0; n < 2; ++n) {
        int col = wc + n * 16 + la;
        #pragma unroll
        for (int j = 0; j < 4; ++j) {
          int r = wr + m * 16 + lb * 4 + j;
          Am[r][col] = f2bf(col <= r ? acc[m][n][j] : 0.f);
        }
      }
  }
  __syncthreads();
  // denominator: den[l] = sum_i Am[l][i] + Q[l].kp
  {
    int l = t >> 2, q = t & 3;
    float s = 0.f;
    #pragma unroll
    for (int i = 0; i < 16; ++i) s += bf2f(Am[l][q * 16 + i]);
    s += __shfl_xor(s, 1);
    s += __shfl_xor(s, 2);
    if (q == 0) {
      float qk = 0.f;
      for (int d = 0; d < 64; ++d) qk += bf2f(Qs[l][d]) * kps[d];
      den_s[l] = s + qk;
    }
  }
  __syncthreads();
  // phase B: num = Am @ V + Q @ P ; write attn = num/(den+eps)
  {
    const int row0 = w * 16;
    f32x4 acc[4];
    #pragma unroll
    for (int n = 0; n < 4; ++n) acc[n] = (f32x4){0.f, 0.f, 0.f, 0.f};
    #pragma unroll
    for (int ks = 0; ks < 2; ++ks) {
      bf16x8 a1 = __builtin_bit_cast(bf16x8, *(const u32x4*)(&Am[row0 + la][ks*32 + lb*8]));
      bf16x8 a2 = __builtin_bit_cast(bf16x8, *(const u32x4*)(&Qs[row0 + la][ks*32 + lb*8]));
      #pragma unroll
      for (int n = 0; n < 4; ++n) {
        bf16x8 b1 = __builtin_bit_cast(bf16x8, *(const u32x4*)(&Vt[n*16 + la][ks*32 + lb*8]));
        acc[n] = __builtin_amdgcn_mfma_f32_16x16x32_bf16(a1, b1, acc[n], 0, 0, 0);
        bf16x8 b2 = __builtin_bit_cast(bf16x8, *(const u32x4*)(&Pts[n*16 + la][ks*32 + lb*8]));
        acc[n] = __builtin_amdgcn_mfma_f32_16x16x32_bf16(a2, b2, acc[n], 0, 0, 0);
      }
    }
    #pragma unroll
    for (int n = 0; n < 4; ++n) {
      int col = n * 16 + la;
      #pragma unroll
      for (int j = 0; j < 4; ++j) {
        int r = row0 + lb * 4 + j;
        float v = acc[n][j] / (den_s[r] + 1e-6f);
        attnb[(size_t)(c * 64 + r) * 1024 + h * 64 + col] = f2bf(v);
      }
    }
  }
}

extern "C" void kernel_launch(void* const* d_in, const int* in_sizes, int n_in,
                              void* d_out, int out_size, void* d_ws, size_t ws_size,
                              hipStream_t stream) {
  const float* x  = (const float*)d_in[0];
  const float* wq = (const float*)d_in[1];
  const float* wk = (const float*)d_in[2];
  const float* wv = (const float*)d_in[3];
  const float* wo = (const float*)d_in[4];
  float* out = (float*)d_out;
  char* ws = (char*)d_ws;
  const size_t MB = 1024 * 1024;
  u16*   xb    = (u16*)(ws + 0 * MB);         // 4 MB
  u16*   wqt   = (u16*)(ws + 4 * MB);         // 2 MB
  u16*   wkt   = (u16*)(ws + 6 * MB);         // 2 MB
  u16*   wvt   = (u16*)(ws + 8 * MB);         // 2 MB
  u16*   wot   = (u16*)(ws + 10 * MB);        // 2 MB
  u16*   Qb    = (u16*)(ws + 12 * MB);        // 4 MB
  u16*   Kb    = (u16*)(ws + 16 * MB);        // 4 MB
  u16*   Vb    = (u16*)(ws + 20 * MB);        // 4 MB
  float* S     = (float*)(ws + 24 * MB);      // 8 MB  (32 chunks x 16 h x 64 m x 64 d)
  u16*   Pt    = (u16*)(ws + 32 * MB);        // 4 MB
  float* ksum  = (float*)(ws + 36 * MB);      // 128 KB
  float* kp    = (float*)(ws + 36 * MB + 128 * 1024); // 128 KB
  u16*   attnb = (u16*)(ws + 37 * MB);        // 4 MB
  float* trig  = (float*)(ws + 41 * MB);      // 512 KB

  conv_x_k<<<1024, 256, 0, stream>>>(x, xb, 2048 * 1024);
  conv_wt_k<<<dim3(32, 32, 4), 256, 0, stream>>>(wq, wk, wv, wo, wqt, wkt, wvt, wot);
  trig_k<<<256, 256, 0, stream>>>(trig);
  gemm_bt<true><<<dim3(8, 16, 3), 256, 0, stream>>>(xb, wqt, wkt, wvt, (void*)Qb, (void*)Kb, (void*)Vb,
                                                    2048, 1024, 1024);
  rope_relu_k<<<8192, 256, 0, stream>>>(Qb, Kb, trig);
  chunk_kv_k<<<dim3(32, 16), 256, 0, stream>>>(Kb, Vb, S, ksum);
  prefix_k<<<256, 256, 0, stream>>>(S, ksum, Pt, kp);
  chunk_out_k<<<dim3(32, 16), 256, 0, stream>>>(Qb, Kb, Vb, Pt, kp, attnb);
  gemm_bt<false><<<dim3(8, 16, 1), 256, 0, stream>>>(attnb, wot, wot, wot, (void*)out, (void*)out, (void*)out,
                                                     2048, 1024, 1024);
}

// Round 3
// 118.780 us; speedup vs baseline: 1.6196x; 1.0343x over previous
//
#include <hip/hip_runtime.h>

typedef unsigned short u16;
typedef unsigned int u32;
typedef __attribute__((ext_vector_type(8))) __bf16 bf16x8;
typedef __attribute__((ext_vector_type(4))) float f32x4;
typedef __attribute__((ext_vector_type(4))) u32 u32x4;

__device__ __forceinline__ u16 f2bf(float f) {
  u32 u = __builtin_bit_cast(u32, f);
  u = (u + 0x7fffu + ((u >> 16) & 1u)) >> 16;
  return (u16)u;
}
__device__ __forceinline__ float bf2f(u16 h) {
  return __builtin_bit_cast(float, (u32)h << 16);
}
// async global->LDS, 16B per lane; lds dest is wave-uniform base + lane*16
__device__ __forceinline__ void async16(const void* g, void* l) {
  __builtin_amdgcn_global_load_lds((const __attribute__((address_space(1))) u32*)g,
                                   (__attribute__((address_space(3))) u32*)l, 16, 0, 0);
}

// ---------------- merged prep: x->bf16 | trig table | weight transpose+bf16 ----------------
__global__ __launch_bounds__(256) void prep_k(const float* __restrict__ x,
    const float* __restrict__ wq, const float* __restrict__ wk,
    const float* __restrict__ wv, const float* __restrict__ wo,
    u16* __restrict__ xb, u16* __restrict__ wqt, u16* __restrict__ wkt,
    u16* __restrict__ wvt, u16* __restrict__ wot, float* __restrict__ trig) {
  __shared__ float tile[32][33];
  int b = blockIdx.x, t = threadIdx.x;
  if (b < 1024) {            // conv x: 2048*1024 elems, 8/thread
    int i = (b * 256 + t) * 8;
    u16 tmp[8];
    #pragma unroll
    for (int j = 0; j < 8; ++j) tmp[j] = f2bf(x[i + j]);
    *(u32x4*)(&xb[i]) = *(u32x4*)tmp;
  } else if (b < 1280) {     // trig: idx = l*32+j over 2048*32
    int idx = (b - 1024) * 256 + t;
    int l = idx >> 5, j = idx & 31;
    float invf = powf(10000.0f, -(float)j * (1.0f / 32.0f));
    float ang = (float)l * invf;
    trig[idx * 2 + 0] = cosf(ang);
    trig[idx * 2 + 1] = sinf(ang);
  } else {                   // weight transpose: 4 mats x 1024 tiles of 32x32
    int bb = b - 1280;
    int z = bb >> 10, tt = bb & 1023;
    const float* w = z == 0 ? wq : z == 1 ? wk : z == 2 ? wv : wo;
    u16* o = z == 0 ? wqt : z == 1 ? wkt : z == 2 ? wvt : wot;
    int tx = t & 31, ty = t >> 5;
    int n0 = (tt & 31) * 32, k0 = (tt >> 5) * 32;
    #pragma unroll
    for (int j = 0; j < 4; ++j) tile[ty + j*8][tx] = w[(size_t)(k0 + ty + j*8) * 1024 + n0 + tx];
    __syncthreads();
    #pragma unroll
    for (int j = 0; j < 4; ++j) o[(size_t)(n0 + ty + j*8) * 1024 + k0 + tx] = f2bf(tile[tx][ty + j*8]);
  }
}

// ---------------- GEMM: C[M][N] = A[M][K] @ Bt[N][K]^T  (bf16 in, fp32 acc) ----------------
// m97 structure: global_load_lds w16, linear LDS, BK=32, 2-barrier K-loop.
// BM x 128 tile, 4 waves, wave = (BM/2) x 64 = MR x 4 frags of 16x16x32.
// MODE 0: f32 out. MODE 2: bf16 out, rope+relu fused unless blockIdx.z==2 (V).
template<int BM, int MODE>
__global__ __launch_bounds__(256) void gemm_bt(const u16* __restrict__ A,
    const u16* __restrict__ B0, const u16* __restrict__ B1, const u16* __restrict__ B2,
    void* C0, void* C1, void* C2, const float* __restrict__ trig, int M, int N, int K)
{
  const u16* B = blockIdx.z == 0 ? B0 : blockIdx.z == 1 ? B1 : B2;
  void* Cv = blockIdx.z == 0 ? C0 : blockIdx.z == 1 ? C1 : C2;
  __shared__ __align__(16) u16 As[BM * 32];    // linear: row*32+col (gload_lds needs linear dest)
  __shared__ __align__(16) u16 Bs[128 * 32];
  const int t = threadIdx.x;
  const int lane = t & 63, w = t >> 6;
  const int la = lane & 15, lb = lane >> 4;
  constexpr int MR = BM / 32;
  const int wr = (w >> 1) * (BM / 2), wc = (w & 1) * 64;
  const int brow = blockIdx.y * BM, bcol = blockIdx.x * 128;
  f32x4 acc[MR][4];
  #pragma unroll
  for (int m = 0; m < MR; ++m)
    #pragma unroll
    for (int n = 0; n < 4; ++n) acc[m][n] = (f32x4){0.f, 0.f, 0.f, 0.f};
  const int srow = lane >> 2, scol = (lane & 3) * 8;  // chunk = 16 rows x 32 cols = 1KB
  for (int k0 = 0; k0 < K; k0 += 32) {
    #pragma unroll
    for (int i = 0; i < BM / 64; ++i) {
      int c = w + i * 4;
      async16(&A[(size_t)(brow + c * 16 + srow) * K + k0 + scol], &As[c * 512]);
    }
    #pragma unroll
    for (int i = 0; i < 2; ++i) {
      int c = w + i * 4;
      async16(&B[(size_t)(bcol + c * 16 + srow) * K + k0 + scol], &Bs[c * 512]);
    }
    __syncthreads();   // vmcnt(0) drained before barrier -> LDS tile ready
    bf16x8 af[MR], bff[4];
    #pragma unroll
    for (int m = 0; m < MR; ++m) af[m] = __builtin_bit_cast(bf16x8, *(const u32x4*)(&As[(wr + m*16 + la) * 32 + lb*8]));
    #pragma unroll
    for (int n = 0; n < 4; ++n) bff[n] = __builtin_bit_cast(bf16x8, *(const u32x4*)(&Bs[(wc + n*16 + la) * 32 + lb*8]));
    #pragma unroll
    for (int m = 0; m < MR; ++m)
      #pragma unroll
      for (int n = 0; n < 4; ++n)
        acc[m][n] = __builtin_amdgcn_mfma_f32_16x16x32_bf16(af[m], bff[n], acc[m][n], 0, 0, 0);
    __syncthreads();   // all waves done reading before next tile's loads
  }
  // C/D layout: row = (lane>>4)*4 + j, col = lane&15  [m89]
  const bool do_rope = (MODE == 2) && (blockIdx.z != 2);
  #pragma unroll
  for (int m = 0; m < MR; ++m) {
    #pragma unroll
    for (int n = 0; n < 4; ++n) {
      int gcol = bcol + wc + n * 16 + la;
      int jj = (gcol & 63) >> 1;
      bool odd = gcol & 1;
      #pragma unroll
      for (int j = 0; j < 4; ++j) {
        int r = brow + wr + m * 16 + lb * 4 + j;
        float v = acc[m][n][j];
        if (MODE == 2) {
          float p = __shfl_xor(v, 1);   // pair partner (col ^ 1) — uniform exec
          if (do_rope) {
            float2 t2 = *(const float2*)(&trig[((size_t)r * 32 + jj) * 2]);
            v = odd ? (p * t2.y + v * t2.x) : (v * t2.x - p * t2.y);
            v = fmaxf(v, 0.f);
          }
          ((u16*)Cv)[(size_t)r * N + gcol] = f2bf(v);
        } else {
          ((float*)Cv)[(size_t)r * N + gcol] = v;
        }
      }
    }
  }
}

// ---------------- per-chunk KV sums: S[c][h][m][d] = sum_i K[i][d]*V[i][m]; ksum[c][h][d] ----------------
__global__ __launch_bounds__(256) void chunk_kv_k(const u16* __restrict__ Kb, const u16* __restrict__ Vb,
                                                  float* __restrict__ S, float* __restrict__ ksum) {
  int c = blockIdx.x, h = blockIdx.y;
  __shared__ __align__(16) float Ks[64][68];
  __shared__ __align__(16) float Vs[64][68];
  int t = threadIdx.x;
  #pragma unroll
  for (int i = 0; i < 2; ++i) {
    int r = i * 32 + (t >> 3), col = (t & 7) * 8;
    size_t g = (size_t)(c * 64 + r) * 1024 + h * 64 + col;
    u32x4 kk = *(const u32x4*)(&Kb[g]);
    u32x4 vv = *(const u32x4*)(&Vb[g]);
    const u16* kp_ = (const u16*)&kk;
    const u16* vp_ = (const u16*)&vv;
    #pragma unroll
    for (int j2 = 0; j2 < 8; ++j2) { Ks[r][col + j2] = bf2f(kp_[j2]); Vs[r][col + j2] = bf2f(vp_[j2]); }
  }
  __syncthreads();
  int m = t >> 2, db = (t & 3) * 16;
  float acc[16];
  #pragma unroll
  for (int d = 0; d < 16; ++d) acc[d] = 0.f;
  for (int i = 0; i < 64; ++i) {
    float vm = Vs[i][m];
    #pragma unroll
    for (int q4 = 0; q4 < 4; ++q4) {
      float4 k4 = *(const float4*)(&Ks[i][db + q4 * 4]);
      acc[q4*4+0] += vm * k4.x; acc[q4*4+1] += vm * k4.y;
      acc[q4*4+2] += vm * k4.z; acc[q4*4+3] += vm * k4.w;
    }
  }
  size_t base = ((size_t)(c * 16 + h) * 64 + m) * 64 + db;
  #pragma unroll
  for (int q4 = 0; q4 < 4; ++q4) *(float4*)(&S[base + q4 * 4]) = *(float4*)(&acc[q4 * 4]);
  if (t < 64) {
    float s = 0.f;
    for (int i = 0; i < 64; ++i) s += Ks[i][t];
    ksum[(c * 16 + h) * 64 + t] = s;
  }
}

// ---------------- exclusive chunk prefix: Pt[c][h][m][d] (bf16), kp[c][h][d] (f32) ----------------
__global__ __launch_bounds__(256) void prefix_k(const float* __restrict__ S, const float* __restrict__ ksum,
                                                u16* __restrict__ Pt, float* __restrict__ kp) {
  int idx = blockIdx.x * 256 + threadIdx.x;   // over 16*4096
  int h = idx >> 12, e = idx & 4095;
  float run = 0.f;
  #pragma unroll
  for (int c = 0; c < 32; ++c) {
    size_t cb = (size_t)(c * 16 + h) << 12;
    Pt[cb + e] = f2bf(run);
    run += S[cb + e];
  }
  if (idx < 1024) {
    int hh = idx >> 6, dd = idx & 63;
    float r2 = 0.f;
    #pragma unroll
    for (int c = 0; c < 32; ++c) {
      kp[(c * 16 + hh) * 64 + dd] = r2;
      r2 += ksum[(c * 16 + hh) * 64 + dd];
    }
  }
}

// ---------------- per-chunk output: num = tril(QK^T)@V + Q@P ; den = rowsum + Q.kp ----------------
__global__ __launch_bounds__(256) void chunk_out_k(const u16* __restrict__ Qb, const u16* __restrict__ Kb,
    const u16* __restrict__ Vb, const u16* __restrict__ Pt, const float* __restrict__ kp,
    u16* __restrict__ attnb)
{
  int c = blockIdx.x, h = blockIdx.y;
  __shared__ __align__(16) u16 Qs[64][72];
  __shared__ __align__(16) u16 Ks2[64][72];
  __shared__ __align__(16) u16 Vt[64][72];   // Vt[m][i] = V[i][m]
  __shared__ __align__(16) u16 Pts[64][72];  // Pts[m][d]
  __shared__ __align__(16) u16 Am[64][72];   // masked QK^T, bf16
  __shared__ float den_s[64];
  __shared__ float kps[64];
  const int t = threadIdx.x;
  const int lane = t & 63, w = t >> 6;
  const int la = lane & 15, lb = lane >> 4;
  #pragma unroll
  for (int i = 0; i < 2; ++i) {
    int r = i * 32 + (t >> 3), col = (t & 7) * 8;
    size_t g = (size_t)(c * 64 + r) * 1024 + h * 64 + col;
    *(u32x4*)(&Qs[r][col]) = *(const u32x4*)(&Qb[g]);
    *(u32x4*)(&Ks2[r][col]) = *(const u32x4*)(&Kb[g]);
    u32x4 vv = *(const u32x4*)(&Vb[g]);
    const u16* vp_ = (const u16*)&vv;
    #pragma unroll
    for (int j2 = 0; j2 < 8; ++j2) {        // lane-rotated j to spread banks
      int jj = (j2 + t) & 7;
      Vt[col + jj][r] = vp_[jj];
    }
    *(u32x4*)(&Pts[r][col]) = *(const u32x4*)(&Pt[(((size_t)(c * 16 + h)) << 12) + (size_t)r * 64 + col]);
  }
  if (t < 64) kps[t] = kp[(c * 16 + h) * 64 + t];
  __syncthreads();
  // phase A: Am = tril(Q @ K^T)
  {
    const int wr = (w >> 1) * 32, wc = (w & 1) * 32;
    f32x4 acc[2][2];
    #pragma unroll
    for (int m = 0; m < 2; ++m)
      #pragma unroll
      for (int n = 0; n < 2; ++n) acc[m][n] = (f32x4){0.f, 0.f, 0.f, 0.f};
    #pragma unroll
    for (int ks = 0; ks < 2; ++ks) {
      bf16x8 af[2], bff[2];
      #pragma unroll
      for (int m = 0; m < 2; ++m) af[m] = __builtin_bit_cast(bf16x8, *(const u32x4*)(&Qs[wr + m*16 + la][ks*32 + lb*8]));
      #pragma unroll
      for (int n = 0; n < 2; ++n) bff[n] = __builtin_bit_cast(bf16x8, *(const u32x4*)(&Ks2[wc + n*16 + la][ks*32 + lb*8]));
      #pragma unroll
      for (int m = 0; m < 2; ++m)
        #pragma unroll
        for (int n = 0; n < 2; ++n)
          acc[m][n] = __builtin_amdgcn_mfma_f32_16x16x32_bf16(af[m], bff[n], acc[m][n], 0, 0, 0);
    }
    #pragma unroll
    for (int m = 0; m < 2; ++m)
      #pragma unroll
      for (int n = 0; n < 2; ++n) {
        int col = wc + n * 16 + la;
        #pragma unroll
        for (int j = 0; j < 4; ++j) {
          int r = wr + m * 16 + lb * 4 + j;
          Am[r][col] = f2bf(col <= r ? acc[m][n][j] : 0.f);
        }
      }
  }
  __syncthreads();
  // denominator: den[l] = sum_i Am[l][i] + Q[l].kp
  {
    int l = t >> 2, q = t & 3;
    float s = 0.f;
    #pragma unroll
    for (int i = 0; i < 16; ++i) s += bf2f(Am[l][q * 16 + i]);
    s += __shfl_xor(s, 1);
    s += __shfl_xor(s, 2);
    if (q == 0) {
      float qk = 0.f;
      for (int d = 0; d < 64; ++d) qk += bf2f(Qs[l][d]) * kps[d];
      den_s[l] = s + qk;
    }
  }
  __syncthreads();
  // phase B: num = Am @ V + Q @ P ; write attn = num/(den+eps)
  {
    const int row0 = w * 16;
    f32x4 acc[4];
    #pragma unroll
    for (int n = 0; n < 4; ++n) acc[n] = (f32x4){0.f, 0.f, 0.f, 0.f};
    #pragma unroll
    for (int ks = 0; ks < 2; ++ks) {
      bf16x8 a1 = __builtin_bit_cast(bf16x8, *(const u32x4*)(&Am[row0 + la][ks*32 + lb*8]));
      bf16x8 a2 = __builtin_bit_cast(bf16x8, *(const u32x4*)(&Qs[row0 + la][ks*32 + lb*8]));
      #pragma unroll
      for (int n = 0; n < 4; ++n) {
        bf16x8 b1 = __builtin_bit_cast(bf16x8, *(const u32x4*)(&Vt[n*16 + la][ks*32 + lb*8]));
        acc[n] = __builtin_amdgcn_mfma_f32_16x16x32_bf16(a1, b1, acc[n], 0, 0, 0);
        bf16x8 b2 = __builtin_bit_cast(bf16x8, *(const u32x4*)(&Pts[n*16 + la][ks*32 + lb*8]));
        acc[n] = __builtin_amdgcn_mfma_f32_16x16x32_bf16(a2, b2, acc[n], 0, 0, 0);
      }
    }
    #pragma unroll
    for (int n = 0; n < 4; ++n) {
      int col = n * 16 + la;
      #pragma unroll
      for (int j = 0; j < 4; ++j) {
        int r = row0 + lb * 4 + j;
        float v = acc[n][j] / (den_s[r] + 1e-6f);
        attnb[(size_t)(c * 64 + r) * 1024 + h * 64 + col] = f2bf(v);
      }
    }
  }
}

extern "C" void kernel_launch(void* const* d_in, const int* in_sizes, int n_in,
                              void* d_out, int out_size, void* d_ws, size_t ws_size,
                              hipStream_t stream) {
  const float* x  = (const float*)d_in[0];
  const float* wq = (const float*)d_in[1];
  const float* wk = (const float*)d_in[2];
  const float* wv = (const float*)d_in[3];
  const float* wo = (const float*)d_in[4];
  float* out = (float*)d_out;
  char* ws = (char*)d_ws;
  const size_t MB = 1024 * 1024;
  u16*   xb    = (u16*)(ws + 0 * MB);         // 4 MB
  u16*   wqt   = (u16*)(ws + 4 * MB);         // 2 MB
  u16*   wkt   = (u16*)(ws + 6 * MB);         // 2 MB
  u16*   wvt   = (u16*)(ws + 8 * MB);         // 2 MB
  u16*   wot   = (u16*)(ws + 10 * MB);        // 2 MB
  u16*   Qb    = (u16*)(ws + 12 * MB);        // 4 MB
  u16*   Kb    = (u16*)(ws + 16 * MB);        // 4 MB
  u16*   Vb    = (u16*)(ws + 20 * MB);        // 4 MB
  float* S     = (float*)(ws + 24 * MB);      // 8 MB  (32 c x 16 h x 64 m x 64 d)
  u16*   Pt    = (u16*)(ws + 32 * MB);        // 4 MB
  float* ksum  = (float*)(ws + 36 * MB);      // 128 KB
  float* kp    = (float*)(ws + 36 * MB + 128 * 1024); // 128 KB
  u16*   attnb = (u16*)(ws + 37 * MB);        // 4 MB
  float* trig  = (float*)(ws + 41 * MB);      // 512 KB

  prep_k<<<1024 + 256 + 4096, 256, 0, stream>>>(x, wq, wk, wv, wo, xb, wqt, wkt, wvt, wot, trig);
  // qkv + fused rope/relu: 128x128 tiles, z in {q,k,v}
  gemm_bt<128, 2><<<dim3(8, 16, 3), 256, 0, stream>>>(xb, wqt, wkt, wvt,
      (void*)Qb, (void*)Kb, (void*)Vb, trig, 2048, 1024, 1024);
  chunk_kv_k<<<dim3(32, 16), 256, 0, stream>>>(Kb, Vb, S, ksum);
  prefix_k<<<256, 256, 0, stream>>>(S, ksum, Pt, kp);
  chunk_out_k<<<dim3(32, 16), 256, 0, stream>>>(Qb, Kb, Vb, Pt, kp, attnb);
  // output projection: 64x128 tiles -> 256 blocks (full machine)
  gemm_bt<64, 0><<<dim3(8, 32, 1), 256, 0, stream>>>(attnb, wot, wot, wot,
      (void*)out, (void*)out, (void*)out, trig, 2048, 1024, 1024);
}

// Round 4
// 104.151 us; speedup vs baseline: 1.8471x; 1.1405x over previous
//
#include <hip/hip_runtime.h>

typedef unsigned short u16;
typedef unsigned int u32;
typedef __attribute__((ext_vector_type(8))) __bf16 bf16x8;
typedef __attribute__((ext_vector_type(4))) float f32x4;
typedef __attribute__((ext_vector_type(4))) u32 u32x4;

__device__ __forceinline__ u16 f2bf(float f) {
  u32 u = __builtin_bit_cast(u32, f);
  u = (u + 0x7fffu + ((u >> 16) & 1u)) >> 16;
  return (u16)u;
}
__device__ __forceinline__ float bf2f(u16 h) {
  return __builtin_bit_cast(float, (u32)h << 16);
}
// async global->LDS, 16B per lane; lds dest is wave-uniform base + lane*16
__device__ __forceinline__ void async16(const void* g, void* l) {
  __builtin_amdgcn_global_load_lds((const __attribute__((address_space(1))) u32*)g,
                                   (__attribute__((address_space(3))) u32*)l, 16, 0, 0);
}

// ---------------- merged prep: x->bf16 | trig table | weight transpose+bf16 ----------------
__global__ __launch_bounds__(256) void prep_k(const float* __restrict__ x,
    const float* __restrict__ wq, const float* __restrict__ wk,
    const float* __restrict__ wv, const float* __restrict__ wo,
    u16* __restrict__ xb, u16* __restrict__ wqt, u16* __restrict__ wkt,
    u16* __restrict__ wvt, u16* __restrict__ wot, float* __restrict__ trig) {
  __shared__ float tile[32][33];
  int b = blockIdx.x, t = threadIdx.x;
  if (b < 1024) {            // conv x: 2048*1024 elems, 8/thread
    int i = (b * 256 + t) * 8;
    u16 tmp[8];
    #pragma unroll
    for (int j = 0; j < 8; ++j) tmp[j] = f2bf(x[i + j]);
    *(u32x4*)(&xb[i]) = *(u32x4*)tmp;
  } else if (b < 1280) {     // trig: idx = l*32+j over 2048*32
    int idx = (b - 1024) * 256 + t;
    int l = idx >> 5, j = idx & 31;
    float invf = powf(10000.0f, -(float)j * (1.0f / 32.0f));
    float ang = (float)l * invf;
    trig[idx * 2 + 0] = cosf(ang);
    trig[idx * 2 + 1] = sinf(ang);
  } else {                   // weight transpose: 4 mats x 1024 tiles of 32x32
    int bb = b - 1280;
    int z = bb >> 10, tt = bb & 1023;
    const float* w = z == 0 ? wq : z == 1 ? wk : z == 2 ? wv : wo;
    u16* o = z == 0 ? wqt : z == 1 ? wkt : z == 2 ? wvt : wot;
    int tx = t & 31, ty = t >> 5;
    int n0 = (tt & 31) * 32, k0 = (tt >> 5) * 32;
    #pragma unroll
    for (int j = 0; j < 4; ++j) tile[ty + j*8][tx] = w[(size_t)(k0 + ty + j*8) * 1024 + n0 + tx];
    __syncthreads();
    #pragma unroll
    for (int j = 0; j < 4; ++j) o[(size_t)(n0 + ty + j*8) * 1024 + k0 + tx] = f2bf(tile[tx][ty + j*8]);
  }
}

// ---------------- GEMM: C = A[M][K] @ B[n][K]^T, 2-phase dbuf, counted vmcnt ----------------
// BM x BN tile, 4 waves (wave = BM/2 x BN/2), 16x16x32 MFMA frags.
// MODE 2: qkv fused (B rows 0..3071 = Wq|Wk|Wv), bf16 out + rope/relu on z<2.
// MODE 0: f32 out to Cf.
template<int BM, int BN, int MODE>
__global__ __launch_bounds__(256) void gemm_dbuf(
    const u16* __restrict__ A, const u16* __restrict__ B,
    u16* __restrict__ Cq, u16* __restrict__ Ck, u16* __restrict__ Cv,
    float* __restrict__ Cf, const float* __restrict__ trig, int K, int NX)
{
  constexpr int MR = BM / 32, NR = BN / 32;
  constexpr int CA = BM / 16, CB = BN / 16;   // 1KB staging chunks
  constexpr int IA = CA / 4, IB = CB / 4;     // issues per wave
  constexpr int LDSZ = (BM + BN) * 32;        // u16 per buffer
  __shared__ __align__(16) u16 lds[2][LDSZ];
  const int t = threadIdx.x;
  const int lane = t & 63, w = t >> 6;
  const int la = lane & 15, lb = lane >> 4;
  // bijective XCD swizzle (nwg % 8 == 0)
  const int nwg = gridDim.x, cpx = nwg >> 3;
  const int hw = blockIdx.x;
  const int logical = (hw & 7) * cpx + (hw >> 3);
  const int bx = logical % NX, by = logical / NX;
  const int brow = by * BM;
  const int bn0 = bx * BN;
  const u16* Bp = B + (size_t)bn0 * K;
  const int wr = (w >> 1) * (BM / 2), wc = (w & 1) * (BN / 2);
  f32x4 acc[MR][NR];
  #pragma unroll
  for (int m = 0; m < MR; ++m)
    #pragma unroll
    for (int n = 0; n < NR; ++n) acc[m][n] = (f32x4){0.f, 0.f, 0.f, 0.f};
  const int srow = lane >> 2, scol = (lane & 3) * 8;

  auto stage = [&](int buf, int kt) {
    int k0 = kt * 32;
    #pragma unroll
    for (int i = 0; i < IA; ++i) {
      int c = w + i * 4;
      async16(&A[(size_t)(brow + c * 16 + srow) * K + k0 + scol], &lds[buf][c * 512]);
    }
    #pragma unroll
    for (int i = 0; i < IB; ++i) {
      int c = w + i * 4;
      async16(&Bp[(size_t)(c * 16 + srow) * K + k0 + scol], &lds[buf][BM * 32 + c * 512]);
    }
  };
  auto compute = [&](int buf) {
    bf16x8 af[MR], bff[NR];
    #pragma unroll
    for (int m = 0; m < MR; ++m)
      af[m] = __builtin_bit_cast(bf16x8, *(const u32x4*)(&lds[buf][(wr + m * 16 + la) * 32 + lb * 8]));
    #pragma unroll
    for (int n = 0; n < NR; ++n)
      bff[n] = __builtin_bit_cast(bf16x8, *(const u32x4*)(&lds[buf][BM * 32 + (wc + n * 16 + la) * 32 + lb * 8]));
    #pragma unroll
    for (int m = 0; m < MR; ++m)
      #pragma unroll
      for (int n = 0; n < NR; ++n)
        acc[m][n] = __builtin_amdgcn_mfma_f32_16x16x32_bf16(af[m], bff[n], acc[m][n], 0, 0, 0);
  };

  const int NT = K / 32;
  stage(0, 0);
  asm volatile("s_waitcnt vmcnt(0)" ::: "memory");
  __builtin_amdgcn_s_barrier();
  for (int kt = 0; kt < NT - 1; ++kt) {
    stage((kt & 1) ^ 1, kt + 1);     // issue next tile's loads (in flight during MFMA)
    compute(kt & 1);
    asm volatile("s_waitcnt vmcnt(0)" ::: "memory");  // next tile landed
    __builtin_amdgcn_s_barrier();
  }
  compute((NT - 1) & 1);

  // C/D layout: row = (lane>>4)*4 + j, col = lane&15  [m89]
  if (MODE == 2) {
    const int z = bn0 >> 10, colz = bn0 & 1023;
    u16* C = z == 0 ? Cq : z == 1 ? Ck : Cv;
    const bool do_rope = z < 2;
    #pragma unroll
    for (int m = 0; m < MR; ++m) {
      #pragma unroll
      for (int n = 0; n < NR; ++n) {
        int gcol = colz + wc + n * 16 + la;
        int jj = (gcol & 63) >> 1;
        bool odd = gcol & 1;
        #pragma unroll
        for (int j = 0; j < 4; ++j) {
          int r = brow + wr + m * 16 + lb * 4 + j;
          float v = acc[m][n][j];
          float p = __shfl_xor(v, 1);   // pair partner (col ^ 1) — uniform exec
          if (do_rope) {
            float2 t2 = *(const float2*)(&trig[((size_t)r * 32 + jj) * 2]);
            v = odd ? (p * t2.y + v * t2.x) : (v * t2.x - p * t2.y);
            v = fmaxf(v, 0.f);
          }
          C[(size_t)r * 1024 + gcol] = f2bf(v);
        }
      }
    }
  } else {
    #pragma unroll
    for (int m = 0; m < MR; ++m) {
      #pragma unroll
      for (int n = 0; n < NR; ++n) {
        int gcol = bn0 + wc + n * 16 + la;
        #pragma unroll
        for (int j = 0; j < 4; ++j) {
          int r = brow + wr + m * 16 + lb * 4 + j;
          Cf[(size_t)r * 1024 + gcol] = acc[m][n][j];
        }
      }
    }
  }
}

// ---------------- per-chunk KV sums: S[c][h][m][d] = sum_i K[i][d]*V[i][m]; ksum[c][h][d] ----------------
__global__ __launch_bounds__(256) void chunk_kv_k(const u16* __restrict__ Kb, const u16* __restrict__ Vb,
                                                  float* __restrict__ S, float* __restrict__ ksum) {
  int c = blockIdx.x, h = blockIdx.y;
  __shared__ __align__(16) float Ks[64][68];
  __shared__ __align__(16) float Vs[64][68];
  int t = threadIdx.x;
  #pragma unroll
  for (int i = 0; i < 2; ++i) {
    int r = i * 32 + (t >> 3), col = (t & 7) * 8;
    size_t g = (size_t)(c * 64 + r) * 1024 + h * 64 + col;
    u32x4 kk = *(const u32x4*)(&Kb[g]);
    u32x4 vv = *(const u32x4*)(&Vb[g]);
    const u16* kp_ = (const u16*)&kk;
    const u16* vp_ = (const u16*)&vv;
    #pragma unroll
    for (int j2 = 0; j2 < 8; ++j2) { Ks[r][col + j2] = bf2f(kp_[j2]); Vs[r][col + j2] = bf2f(vp_[j2]); }
  }
  __syncthreads();
  int m = t >> 2, db = (t & 3) * 16;
  float acc[16];
  #pragma unroll
  for (int d = 0; d < 16; ++d) acc[d] = 0.f;
  for (int i = 0; i < 64; ++i) {
    float vm = Vs[i][m];
    #pragma unroll
    for (int q4 = 0; q4 < 4; ++q4) {
      float4 k4 = *(const float4*)(&Ks[i][db + q4 * 4]);
      acc[q4*4+0] += vm * k4.x; acc[q4*4+1] += vm * k4.y;
      acc[q4*4+2] += vm * k4.z; acc[q4*4+3] += vm * k4.w;
    }
  }
  size_t base = ((size_t)(c * 16 + h) * 64 + m) * 64 + db;
  #pragma unroll
  for (int q4 = 0; q4 < 4; ++q4) *(float4*)(&S[base + q4 * 4]) = *(float4*)(&acc[q4 * 4]);
  if (t < 64) {
    float s = 0.f;
    for (int i = 0; i < 64; ++i) s += Ks[i][t];
    ksum[(c * 16 + h) * 64 + t] = s;
  }
}

// ---------------- exclusive chunk prefix: Pt[c][h][m][d] (bf16), kp[c][h][d] (f32) ----------------
__global__ __launch_bounds__(256) void prefix_k(const float* __restrict__ S, const float* __restrict__ ksum,
                                                u16* __restrict__ Pt, float* __restrict__ kp) {
  int idx = blockIdx.x * 256 + threadIdx.x;   // over 16*4096
  int h = idx >> 12, e = idx & 4095;
  float run = 0.f;
  #pragma unroll
  for (int c = 0; c < 32; ++c) {
    size_t cb = (size_t)(c * 16 + h) << 12;
    Pt[cb + e] = f2bf(run);
    run += S[cb + e];
  }
  if (idx < 1024) {
    int hh = idx >> 6, dd = idx & 63;
    float r2 = 0.f;
    #pragma unroll
    for (int c = 0; c < 32; ++c) {
      kp[(c * 16 + hh) * 64 + dd] = r2;
      r2 += ksum[(c * 16 + hh) * 64 + dd];
    }
  }
}

// ---------------- per-chunk output: num = tril(QK^T)@V + Q@P ; den = rowsum + Q.kp ----------------
__global__ __launch_bounds__(256) void chunk_out_k(const u16* __restrict__ Qb, const u16* __restrict__ Kb,
    const u16* __restrict__ Vb, const u16* __restrict__ Pt, const float* __restrict__ kp,
    u16* __restrict__ attnb)
{
  int c = blockIdx.x, h = blockIdx.y;
  __shared__ __align__(16) u16 Qs[64][72];
  __shared__ __align__(16) u16 Ks2[64][72];
  __shared__ __align__(16) u16 Vt[64][72];   // Vt[m][i] = V[i][m]
  __shared__ __align__(16) u16 Pts[64][72];  // Pts[m][d]
  __shared__ __align__(16) u16 Am[64][72];   // masked QK^T, bf16
  __shared__ float den_s[64];
  __shared__ float kps[64];
  const int t = threadIdx.x;
  const int lane = t & 63, w = t >> 6;
  const int la = lane & 15, lb = lane >> 4;
  #pragma unroll
  for (int i = 0; i < 2; ++i) {
    int r = i * 32 + (t >> 3), col = (t & 7) * 8;
    size_t g = (size_t)(c * 64 + r) * 1024 + h * 64 + col;
    *(u32x4*)(&Qs[r][col]) = *(const u32x4*)(&Qb[g]);
    *(u32x4*)(&Ks2[r][col]) = *(const u32x4*)(&Kb[g]);
    u32x4 vv = *(const u32x4*)(&Vb[g]);
    const u16* vp_ = (const u16*)&vv;
    #pragma unroll
    for (int j2 = 0; j2 < 8; ++j2) {        // lane-rotated j to spread banks
      int jj = (j2 + t) & 7;
      Vt[col + jj][r] = vp_[jj];
    }
    *(u32x4*)(&Pts[r][col]) = *(const u32x4*)(&Pt[(((size_t)(c * 16 + h)) << 12) + (size_t)r * 64 + col]);
  }
  if (t < 64) kps[t] = kp[(c * 16 + h) * 64 + t];
  __syncthreads();
  // phase A: Am = tril(Q @ K^T)
  {
    const int wr = (w >> 1) * 32, wc = (w & 1) * 32;
    f32x4 acc[2][2];
    #pragma unroll
    for (int m = 0; m < 2; ++m)
      #pragma unroll
      for (int n = 0; n < 2; ++n) acc[m][n] = (f32x4){0.f, 0.f, 0.f, 0.f};
    #pragma unroll
    for (int ks = 0; ks < 2; ++ks) {
      bf16x8 af[2], bff[2];
      #pragma unroll
      for (int m = 0; m < 2; ++m) af[m] = __builtin_bit_cast(bf16x8, *(const u32x4*)(&Qs[wr + m*16 + la][ks*32 + lb*8]));
      #pragma unroll
      for (int n = 0; n < 2; ++n) bff[n] = __builtin_bit_cast(bf16x8, *(const u32x4*)(&Ks2[wc + n*16 + la][ks*32 + lb*8]));
      #pragma unroll
      for (int m = 0; m < 2; ++m)
        #pragma unroll
        for (int n = 0; n < 2; ++n)
          acc[m][n] = __builtin_amdgcn_mfma_f32_16x16x32_bf16(af[m], bff[n], acc[m][n], 0, 0, 0);
    }
    #pragma unroll
    for (int m = 0; m < 2; ++m)
      #pragma unroll
      for (int n = 0; n < 2; ++n) {
        int col = wc + n * 16 + la;
        #pragma unroll
        for (int j = 0; j < 4; ++j) {
          int r = wr + m * 16 + lb * 4 + j;
          Am[r][col] = f2bf(col <= r ? acc[m][n][j] : 0.f);
        }
      }
  }
  __syncthreads();
  // denominator: den[l] = sum_i Am[l][i] + Q[l].kp
  {
    int l = t >> 2, q = t & 3;
    float s = 0.f;
    #pragma unroll
    for (int i = 0; i < 16; ++i) s += bf2f(Am[l][q * 16 + i]);
    s += __shfl_xor(s, 1);
    s += __shfl_xor(s, 2);
    if (q == 0) {
      float qk = 0.f;
      for (int d = 0; d < 64; ++d) qk += bf2f(Qs[l][d]) * kps[d];
      den_s[l] = s + qk;
    }
  }
  __syncthreads();
  // phase B: num = Am @ V + Q @ P ; write attn = num/(den+eps)
  {
    const int row0 = w * 16;
    f32x4 acc[4];
    #pragma unroll
    for (int n = 0; n < 4; ++n) acc[n] = (f32x4){0.f, 0.f, 0.f, 0.f};
    #pragma unroll
    for (int ks = 0; ks < 2; ++ks) {
      bf16x8 a1 = __builtin_bit_cast(bf16x8, *(const u32x4*)(&Am[row0 + la][ks*32 + lb*8]));
      bf16x8 a2 = __builtin_bit_cast(bf16x8, *(const u32x4*)(&Qs[row0 + la][ks*32 + lb*8]));
      #pragma unroll
      for (int n = 0; n < 4; ++n) {
        bf16x8 b1 = __builtin_bit_cast(bf16x8, *(const u32x4*)(&Vt[n*16 + la][ks*32 + lb*8]));
        acc[n] = __builtin_amdgcn_mfma_f32_16x16x32_bf16(a1, b1, acc[n], 0, 0, 0);
        bf16x8 b2 = __builtin_bit_cast(bf16x8, *(const u32x4*)(&Pts[n*16 + la][ks*32 + lb*8]));
        acc[n] = __builtin_amdgcn_mfma_f32_16x16x32_bf16(a2, b2, acc[n], 0, 0, 0);
      }
    }
    #pragma unroll
    for (int n = 0; n < 4; ++n) {
      int col = n * 16 + la;
      #pragma unroll
      for (int j = 0; j < 4; ++j) {
        int r = row0 + lb * 4 + j;
        float v = acc[n][j] / (den_s[r] + 1e-6f);
        attnb[(size_t)(c * 64 + r) * 1024 + h * 64 + col] = f2bf(v);
      }
    }
  }
}

extern "C" void kernel_launch(void* const* d_in, const int* in_sizes, int n_in,
                              void* d_out, int out_size, void* d_ws, size_t ws_size,
                              hipStream_t stream) {
  const float* x  = (const float*)d_in[0];
  const float* wq = (const float*)d_in[1];
  const float* wk = (const float*)d_in[2];
  const float* wv = (const float*)d_in[3];
  const float* wo = (const float*)d_in[4];
  float* out = (float*)d_out;
  char* ws = (char*)d_ws;
  const size_t MB = 1024 * 1024;
  u16*   xb    = (u16*)(ws + 0 * MB);         // 4 MB
  u16*   wqt   = (u16*)(ws + 4 * MB);         // 2 MB  (wqt|wkt|wvt contiguous = fused B, N=3072)
  u16*   wkt   = (u16*)(ws + 6 * MB);         // 2 MB
  u16*   wvt   = (u16*)(ws + 8 * MB);         // 2 MB
  u16*   wot   = (u16*)(ws + 10 * MB);        // 2 MB
  u16*   Qb    = (u16*)(ws + 12 * MB);        // 4 MB
  u16*   Kb    = (u16*)(ws + 16 * MB);        // 4 MB
  u16*   Vb    = (u16*)(ws + 20 * MB);        // 4 MB
  float* S     = (float*)(ws + 24 * MB);      // 8 MB  (32 c x 16 h x 64 m x 64 d)
  u16*   Pt    = (u16*)(ws + 32 * MB);        // 4 MB
  float* ksum  = (float*)(ws + 36 * MB);      // 128 KB
  float* kp    = (float*)(ws + 36 * MB + 128 * 1024); // 128 KB
  u16*   attnb = (u16*)(ws + 37 * MB);        // 4 MB
  float* trig  = (float*)(ws + 41 * MB);      // 512 KB

  prep_k<<<1024 + 256 + 4096, 256, 0, stream>>>(x, wq, wk, wv, wo, xb, wqt, wkt, wvt, wot, trig);
  // qkv fused over N=3072: 64x128 tiles -> 768 blocks (3/CU)
  gemm_dbuf<64, 128, 2><<<768, 256, 0, stream>>>(xb, wqt, Qb, Kb, Vb, nullptr, trig, 1024, 24);
  chunk_kv_k<<<dim3(32, 16), 256, 0, stream>>>(Kb, Vb, S, ksum);
  prefix_k<<<256, 256, 0, stream>>>(S, ksum, Pt, kp);
  chunk_out_k<<<dim3(32, 16), 256, 0, stream>>>(Qb, Kb, Vb, Pt, kp, attnb);
  // output projection: 64x64 tiles -> 512 blocks (2/CU)
  gemm_dbuf<64, 64, 0><<<512, 256, 0, stream>>>(attnb, wot, nullptr, nullptr, nullptr, out, trig, 1024, 16);
}

// Round 5
// 96.487 us; speedup vs baseline: 1.9938x; 1.0794x over previous
//
#include <hip/hip_runtime.h>

typedef unsigned short u16;
typedef unsigned int u32;
typedef __attribute__((ext_vector_type(8))) __bf16 bf16x8;
typedef __attribute__((ext_vector_type(4))) float f32x4;
typedef __attribute__((ext_vector_type(4))) u32 u32x4;

__device__ __forceinline__ u16 f2bf(float f) {
  u32 u = __builtin_bit_cast(u32, f);
  u = (u + 0x7fffu + ((u >> 16) & 1u)) >> 16;
  return (u16)u;
}
__device__ __forceinline__ float bf2f(u16 h) {
  return __builtin_bit_cast(float, (u32)h << 16);
}
// async global->LDS, 16B per lane; lds dest is wave-uniform base + lane*16
__device__ __forceinline__ void async16(const void* g, void* l) {
  __builtin_amdgcn_global_load_lds((const __attribute__((address_space(1))) u32*)g,
                                   (__attribute__((address_space(3))) u32*)l, 16, 0, 0);
}

// ---------------- merged prep: x->bf16 | trig table | weight transpose+bf16 ----------------
__global__ __launch_bounds__(256) void prep_k(const float* __restrict__ x,
    const float* __restrict__ wq, const float* __restrict__ wk,
    const float* __restrict__ wv, const float* __restrict__ wo,
    u16* __restrict__ xb, u16* __restrict__ wqt, u16* __restrict__ wkt,
    u16* __restrict__ wvt, u16* __restrict__ wot, float* __restrict__ trig) {
  __shared__ float tile[32][33];
  int b = blockIdx.x, t = threadIdx.x;
  if (b < 1024) {            // conv x: 2048*1024 elems, 8/thread
    int i = (b * 256 + t) * 8;
    u16 tmp[8];
    #pragma unroll
    for (int j = 0; j < 8; ++j) tmp[j] = f2bf(x[i + j]);
    *(u32x4*)(&xb[i]) = *(u32x4*)tmp;
  } else if (b < 1280) {     // trig: idx = l*32+j over 2048*32
    int idx = (b - 1024) * 256 + t;
    int l = idx >> 5, j = idx & 31;
    float invf = powf(10000.0f, -(float)j * (1.0f / 32.0f));
    float ang = (float)l * invf;
    trig[idx * 2 + 0] = cosf(ang);
    trig[idx * 2 + 1] = sinf(ang);
  } else {                   // weight transpose: 4 mats x 1024 tiles of 32x32
    int bb = b - 1280;
    int z = bb >> 10, tt = bb & 1023;
    const float* w = z == 0 ? wq : z == 1 ? wk : z == 2 ? wv : wo;
    u16* o = z == 0 ? wqt : z == 1 ? wkt : z == 2 ? wvt : wot;
    int tx = t & 31, ty = t >> 5;
    int n0 = (tt & 31) * 32, k0 = (tt >> 5) * 32;
    #pragma unroll
    for (int j = 0; j < 4; ++j) tile[ty + j*8][tx] = w[(size_t)(k0 + ty + j*8) * 1024 + n0 + tx];
    __syncthreads();
    #pragma unroll
    for (int j = 0; j < 4; ++j) o[(size_t)(n0 + ty + j*8) * 1024 + k0 + tx] = f2bf(tile[tx][ty + j*8]);
  }
}

// ---------------- GEMM: C = A[M][K] @ B[n][K]^T, BK=64, 2-phase dbuf, XOR-swizzled LDS ----
// Swizzle (rule #21, both-sides): gload_lds writes linearly; global SOURCE slot is
// pre-permuted (slot = (lane&7)^(lane>>3)); ds_read applies slot ^= (row&7).
// Chunk = 8 rows x 64 cols x 2B = 1KB per issue (lane covers 16B = slot of 8 per row).
// MODE 2: qkv fused (B = Wq|Wk|Wv rows, N=3072), bf16 out + rope/relu on z<2.
// MODE 0: f32 out to Cf.
template<int BM, int BN, int MODE>
__global__ __launch_bounds__(256) void gemm_dbuf(
    const u16* __restrict__ A, const u16* __restrict__ B,
    u16* __restrict__ Cq, u16* __restrict__ Ck, u16* __restrict__ Cv,
    float* __restrict__ Cf, const float* __restrict__ trig, int K, int NX)
{
  constexpr int MR = BM / 32, NR = BN / 32;
  constexpr int IA = BM / 32, IB = BN / 32;     // 1KB-chunks per wave (chunks/4)
  constexpr int LDSZ = (BM + BN) * 64;          // u16 per buffer
  __shared__ __align__(16) u16 lds[2][LDSZ];
  const int t = threadIdx.x;
  const int lane = t & 63, w = t >> 6;
  const int la = lane & 15, lb = lane >> 4;
  // bijective XCD swizzle (nwg % 8 == 0)
  const int nwg = gridDim.x, cpx = nwg >> 3;
  const int hw = blockIdx.x;
  const int logical = (hw & 7) * cpx + (hw >> 3);
  const int bx = logical % NX, by = logical / NX;
  const int brow = by * BM;
  const int bn0 = bx * BN;
  const u16* Bp = B + (size_t)bn0 * K;
  const int wr = (w >> 1) * (BM / 2), wc = (w & 1) * (BN / 2);
  f32x4 acc[MR][NR];
  #pragma unroll
  for (int m = 0; m < MR; ++m)
    #pragma unroll
    for (int n = 0; n < NR; ++n) acc[m][n] = (f32x4){0.f, 0.f, 0.f, 0.f};
  const int srow8 = lane >> 3;                  // row within 8-row chunk
  const int sw8 = (((lane & 7) ^ srow8) << 3);  // pre-swizzled source col (u16)

  auto stage = [&](int buf, int kt) {
    const int k0 = kt * 64;
    #pragma unroll
    for (int i = 0; i < IA; ++i) {
      int c = w + i * 4;
      async16(&A[(size_t)(brow + c * 8 + srow8) * K + k0 + sw8], &lds[buf][c * 512]);
    }
    #pragma unroll
    for (int i = 0; i < IB; ++i) {
      int c = w + i * 4;
      async16(&Bp[(size_t)(c * 8 + srow8) * K + k0 + sw8], &lds[buf][BM * 64 + c * 512]);
    }
  };
  auto compute = [&](int buf) {
    #pragma unroll
    for (int ks = 0; ks < 2; ++ks) {
      bf16x8 af[MR], bff[NR];
      const int slot = ks * 4 + lb;
      #pragma unroll
      for (int m = 0; m < MR; ++m) {
        int row = wr + m * 16 + la;
        af[m] = __builtin_bit_cast(bf16x8,
            *(const u32x4*)(&lds[buf][row * 64 + ((slot ^ (row & 7)) << 3)]));
      }
      #pragma unroll
      for (int n = 0; n < NR; ++n) {
        int row = wc + n * 16 + la;
        bff[n] = __builtin_bit_cast(bf16x8,
            *(const u32x4*)(&lds[buf][BM * 64 + row * 64 + ((slot ^ (row & 7)) << 3)]));
      }
      #pragma unroll
      for (int m = 0; m < MR; ++m)
        #pragma unroll
        for (int n = 0; n < NR; ++n)
          acc[m][n] = __builtin_amdgcn_mfma_f32_16x16x32_bf16(af[m], bff[n], acc[m][n], 0, 0, 0);
    }
  };

  const int NT = K / 64;
  stage(0, 0);
  asm volatile("s_waitcnt vmcnt(0)" ::: "memory");
  __builtin_amdgcn_s_barrier();
  for (int kt = 0; kt < NT - 1; ++kt) {
    stage((kt & 1) ^ 1, kt + 1);     // next tile's loads in flight during MFMA
    compute(kt & 1);
    asm volatile("s_waitcnt vmcnt(0)" ::: "memory");
    __builtin_amdgcn_s_barrier();
  }
  compute((NT - 1) & 1);

  // C/D layout: row = (lane>>4)*4 + j, col = lane&15  [m89]
  if (MODE == 2) {
    const int z = bn0 >> 10, colz = bn0 & 1023;
    u16* C = z == 0 ? Cq : z == 1 ? Ck : Cv;
    const bool do_rope = z < 2;
    #pragma unroll
    for (int m = 0; m < MR; ++m) {
      #pragma unroll
      for (int n = 0; n < NR; ++n) {
        int gcol = colz + wc + n * 16 + la;
        int jj = (gcol & 63) >> 1;
        bool odd = gcol & 1;
        #pragma unroll
        for (int j = 0; j < 4; ++j) {
          int r = brow + wr + m * 16 + lb * 4 + j;
          float v = acc[m][n][j];
          float p = __shfl_xor(v, 1);   // pair partner (col ^ 1) — uniform exec
          if (do_rope) {
            float2 t2 = *(const float2*)(&trig[((size_t)r * 32 + jj) * 2]);
            v = odd ? (p * t2.y + v * t2.x) : (v * t2.x - p * t2.y);
            v = fmaxf(v, 0.f);
          }
          C[(size_t)r * 1024 + gcol] = f2bf(v);
        }
      }
    }
  } else {
    #pragma unroll
    for (int m = 0; m < MR; ++m) {
      #pragma unroll
      for (int n = 0; n < NR; ++n) {
        int gcol = bn0 + wc + n * 16 + la;
        #pragma unroll
        for (int j = 0; j < 4; ++j) {
          int r = brow + wr + m * 16 + lb * 4 + j;
          Cf[(size_t)r * 1024 + gcol] = acc[m][n][j];
        }
      }
    }
  }
}

// ---------------- per-chunk KV sums: S[c][h][m][d] = sum_i K[i][d]*V[i][m]; ksum[c][h][d] ----------------
__global__ __launch_bounds__(256) void chunk_kv_k(const u16* __restrict__ Kb, const u16* __restrict__ Vb,
                                                  float* __restrict__ S, float* __restrict__ ksum) {
  int c = blockIdx.x, h = blockIdx.y;
  __shared__ __align__(16) float Ks[64][68];
  __shared__ __align__(16) float Vs[64][68];
  int t = threadIdx.x;
  #pragma unroll
  for (int i = 0; i < 2; ++i) {
    int r = i * 32 + (t >> 3), col = (t & 7) * 8;
    size_t g = (size_t)(c * 64 + r) * 1024 + h * 64 + col;
    u32x4 kk = *(const u32x4*)(&Kb[g]);
    u32x4 vv = *(const u32x4*)(&Vb[g]);
    const u16* kp_ = (const u16*)&kk;
    const u16* vp_ = (const u16*)&vv;
    #pragma unroll
    for (int j2 = 0; j2 < 8; ++j2) { Ks[r][col + j2] = bf2f(kp_[j2]); Vs[r][col + j2] = bf2f(vp_[j2]); }
  }
  __syncthreads();
  int m = t >> 2, db = (t & 3) * 16;
  float acc[16];
  #pragma unroll
  for (int d = 0; d < 16; ++d) acc[d] = 0.f;
  for (int i = 0; i < 64; ++i) {
    float vm = Vs[i][m];
    #pragma unroll
    for (int q4 = 0; q4 < 4; ++q4) {
      float4 k4 = *(const float4*)(&Ks[i][db + q4 * 4]);
      acc[q4*4+0] += vm * k4.x; acc[q4*4+1] += vm * k4.y;
      acc[q4*4+2] += vm * k4.z; acc[q4*4+3] += vm * k4.w;
    }
  }
  size_t base = ((size_t)(c * 16 + h) * 64 + m) * 64 + db;
  #pragma unroll
  for (int q4 = 0; q4 < 4; ++q4) *(float4*)(&S[base + q4 * 4]) = *(float4*)(&acc[q4 * 4]);
  if (t < 64) {
    float s = 0.f;
    for (int i = 0; i < 64; ++i) s += Ks[i][t];
    ksum[(c * 16 + h) * 64 + t] = s;
  }
}

// ---------------- exclusive chunk prefix: Pt[c][h][m][d] (bf16), kp[c][h][d] (f32) ----------------
__global__ __launch_bounds__(256) void prefix_k(const float* __restrict__ S, const float* __restrict__ ksum,
                                                u16* __restrict__ Pt, float* __restrict__ kp) {
  int idx = blockIdx.x * 256 + threadIdx.x;   // over 16*4096
  int h = idx >> 12, e = idx & 4095;
  float run = 0.f;
  #pragma unroll
  for (int c = 0; c < 32; ++c) {
    size_t cb = (size_t)(c * 16 + h) << 12;
    Pt[cb + e] = f2bf(run);
    run += S[cb + e];
  }
  if (idx < 1024) {
    int hh = idx >> 6, dd = idx & 63;
    float r2 = 0.f;
    #pragma unroll
    for (int c = 0; c < 32; ++c) {
      kp[(c * 16 + hh) * 64 + dd] = r2;
      r2 += ksum[(c * 16 + hh) * 64 + dd];
    }
  }
}

// ---------------- per-chunk output: num = tril(QK^T)@V + Q@P ; den = rowsum + Q.kp ----------------
__global__ __launch_bounds__(256) void chunk_out_k(const u16* __restrict__ Qb, const u16* __restrict__ Kb,
    const u16* __restrict__ Vb, const u16* __restrict__ Pt, const float* __restrict__ kp,
    u16* __restrict__ attnb)
{
  int c = blockIdx.x, h = blockIdx.y;
  __shared__ __align__(16) u16 Qs[64][72];
  __shared__ __align__(16) u16 Ks2[64][72];
  __shared__ __align__(16) u16 Vt[64][72];   // Vt[m][i] = V[i][m]
  __shared__ __align__(16) u16 Pts[64][72];  // Pts[m][d]
  __shared__ __align__(16) u16 Am[64][72];   // masked QK^T, bf16
  __shared__ float den_s[64];
  __shared__ float kps[64];
  const int t = threadIdx.x;
  const int lane = t & 63, w = t >> 6;
  const int la = lane & 15, lb = lane >> 4;
  #pragma unroll
  for (int i = 0; i < 2; ++i) {
    int r = i * 32 + (t >> 3), col = (t & 7) * 8;
    size_t g = (size_t)(c * 64 + r) * 1024 + h * 64 + col;
    *(u32x4*)(&Qs[r][col]) = *(const u32x4*)(&Qb[g]);
    *(u32x4*)(&Ks2[r][col]) = *(const u32x4*)(&Kb[g]);
    u32x4 vv = *(const u32x4*)(&Vb[g]);
    const u16* vp_ = (const u16*)&vv;
    #pragma unroll
    for (int j2 = 0; j2 < 8; ++j2) {        // lane-rotated j to spread banks
      int jj = (j2 + t) & 7;
      Vt[col + jj][r] = vp_[jj];
    }
    *(u32x4*)(&Pts[r][col]) = *(const u32x4*)(&Pt[(((size_t)(c * 16 + h)) << 12) + (size_t)r * 64 + col]);
  }
  if (t < 64) kps[t] = kp[(c * 16 + h) * 64 + t];
  __syncthreads();
  // phase A: Am = tril(Q @ K^T)
  {
    const int wr = (w >> 1) * 32, wc = (w & 1) * 32;
    f32x4 acc[2][2];
    #pragma unroll
    for (int m = 0; m < 2; ++m)
      #pragma unroll
      for (int n = 0; n < 2; ++n) acc[m][n] = (f32x4){0.f, 0.f, 0.f, 0.f};
    #pragma unroll
    for (int ks = 0; ks < 2; ++ks) {
      bf16x8 af[2], bff[2];
      #pragma unroll
      for (int m = 0; m < 2; ++m) af[m] = __builtin_bit_cast(bf16x8, *(const u32x4*)(&Qs[wr + m*16 + la][ks*32 + lb*8]));
      #pragma unroll
      for (int n = 0; n < 2; ++n) bff[n] = __builtin_bit_cast(bf16x8, *(const u32x4*)(&Ks2[wc + n*16 + la][ks*32 + lb*8]));
      #pragma unroll
      for (int m = 0; m < 2; ++m)
        #pragma unroll
        for (int n = 0; n < 2; ++n)
          acc[m][n] = __builtin_amdgcn_mfma_f32_16x16x32_bf16(af[m], bff[n], acc[m][n], 0, 0, 0);
    }
    #pragma unroll
    for (int m = 0; m < 2; ++m)
      #pragma unroll
      for (int n = 0; n < 2; ++n) {
        int col = wc + n * 16 + la;
        #pragma unroll
        for (int j = 0; j < 4; ++j) {
          int r = wr + m * 16 + lb * 4 + j;
          Am[r][col] = f2bf(col <= r ? acc[m][n][j] : 0.f);
        }
      }
  }
  __syncthreads();
  // denominator: den[l] = sum_i Am[l][i] + Q[l].kp
  {
    int l = t >> 2, q = t & 3;
    float s = 0.f;
    #pragma unroll
    for (int i = 0; i < 16; ++i) s += bf2f(Am[l][q * 16 + i]);
    s += __shfl_xor(s, 1);
    s += __shfl_xor(s, 2);
    if (q == 0) {
      float qk = 0.f;
      for (int d = 0; d < 64; ++d) qk += bf2f(Qs[l][d]) * kps[d];
      den_s[l] = s + qk;
    }
  }
  __syncthreads();
  // phase B: num = Am @ V + Q @ P ; write attn = num/(den+eps)
  {
    const int row0 = w * 16;
    f32x4 acc[4];
    #pragma unroll
    for (int n = 0; n < 4; ++n) acc[n] = (f32x4){0.f, 0.f, 0.f, 0.f};
    #pragma unroll
    for (int ks = 0; ks < 2; ++ks) {
      bf16x8 a1 = __builtin_bit_cast(bf16x8, *(const u32x4*)(&Am[row0 + la][ks*32 + lb*8]));
      bf16x8 a2 = __builtin_bit_cast(bf16x8, *(const u32x4*)(&Qs[row0 + la][ks*32 + lb*8]));
      #pragma unroll
      for (int n = 0; n < 4; ++n) {
        bf16x8 b1 = __builtin_bit_cast(bf16x8, *(const u32x4*)(&Vt[n*16 + la][ks*32 + lb*8]));
        acc[n] = __builtin_amdgcn_mfma_f32_16x16x32_bf16(a1, b1, acc[n], 0, 0, 0);
        bf16x8 b2 = __builtin_bit_cast(bf16x8, *(const u32x4*)(&Pts[n*16 + la][ks*32 + lb*8]));
        acc[n] = __builtin_amdgcn_mfma_f32_16x16x32_bf16(a2, b2, acc[n], 0, 0, 0);
      }
    }
    #pragma unroll
    for (int n = 0; n < 4; ++n) {
      int col = n * 16 + la;
      #pragma unroll
      for (int j = 0; j < 4; ++j) {
        int r = row0 + lb * 4 + j;
        float v = acc[n][j] / (den_s[r] + 1e-6f);
        attnb[(size_t)(c * 64 + r) * 1024 + h * 64 + col] = f2bf(v);
      }
    }
  }
}

extern "C" void kernel_launch(void* const* d_in, const int* in_sizes, int n_in,
                              void* d_out, int out_size, void* d_ws, size_t ws_size,
                              hipStream_t stream) {
  const float* x  = (const float*)d_in[0];
  const float* wq = (const float*)d_in[1];
  const float* wk = (const float*)d_in[2];
  const float* wv = (const float*)d_in[3];
  const float* wo = (const float*)d_in[4];
  float* out = (float*)d_out;
  char* ws = (char*)d_ws;
  const size_t MB = 1024 * 1024;
  u16*   xb    = (u16*)(ws + 0 * MB);         // 4 MB
  u16*   wqt   = (u16*)(ws + 4 * MB);         // 2 MB  (wqt|wkt|wvt contiguous = fused B, N=3072)
  u16*   wkt   = (u16*)(ws + 6 * MB);         // 2 MB
  u16*   wvt   = (u16*)(ws + 8 * MB);         // 2 MB
  u16*   wot   = (u16*)(ws + 10 * MB);        // 2 MB
  u16*   Qb    = (u16*)(ws + 12 * MB);        // 4 MB
  u16*   Kb    = (u16*)(ws + 16 * MB);        // 4 MB
  u16*   Vb    = (u16*)(ws + 20 * MB);        // 4 MB
  float* S     = (float*)(ws + 24 * MB);      // 8 MB  (32 c x 16 h x 64 m x 64 d)
  u16*   Pt    = (u16*)(ws + 32 * MB);        // 4 MB
  float* ksum  = (float*)(ws + 36 * MB);      // 128 KB
  float* kp    = (float*)(ws + 36 * MB + 128 * 1024); // 128 KB
  u16*   attnb = (u16*)(ws + 37 * MB);        // 4 MB
  float* trig  = (float*)(ws + 41 * MB);      // 512 KB

  prep_k<<<1024 + 256 + 4096, 256, 0, stream>>>(x, wq, wk, wv, wo, xb, wqt, wkt, wvt, wot, trig);
  // qkv fused over N=3072: 64x128 tiles -> 768 blocks (3/CU, 48KB LDS -> full residency)
  gemm_dbuf<64, 128, 2><<<768, 256, 0, stream>>>(xb, wqt, Qb, Kb, Vb, nullptr, trig, 1024, 24);
  chunk_kv_k<<<dim3(32, 16), 256, 0, stream>>>(Kb, Vb, S, ksum);
  prefix_k<<<256, 256, 0, stream>>>(S, ksum, Pt, kp);
  chunk_out_k<<<dim3(32, 16), 256, 0, stream>>>(Qb, Kb, Vb, Pt, kp, attnb);
  // output projection: 64x64 tiles -> 512 blocks (2/CU)
  gemm_dbuf<64, 64, 0><<<512, 256, 0, stream>>>(attnb, wot, nullptr, nullptr, nullptr, out, trig, 1024, 16);
}